// Round 2
// baseline (244.927 us; speedup 1.0000x reference)
//
#include <hip/hip_runtime.h>

#define DIM 1024
#define NH 16
#define HD 64
#define BB 2
#define LL 2048
#define BL (BB*LL)     // 4096
#define NQKV (3*DIM)   // 3072

typedef __bf16 bf16;
typedef __bf16 bf16x4 __attribute__((ext_vector_type(4)));
typedef __bf16 bf16x8 __attribute__((ext_vector_type(8)));
typedef float  f32x4  __attribute__((ext_vector_type(4)));

// 0.125 * log2(e): fold head-dim scale + base-2 conversion into Q
#define QSCALE 0.1803368801111204f

typedef __attribute__((address_space(3))) unsigned int lds_u32;
typedef __attribute__((address_space(1))) unsigned int glb_u32;

// async global->LDS, 16B per lane. LDS dest = wave-uniform base + lane*16.
__device__ __forceinline__ void gld_lds16(const bf16* g, bf16* l) {
    __builtin_amdgcn_global_load_lds((const glb_u32*)g, (lds_u32*)l, 16, 0, 0);
}

// One kernel for all three fp32->bf16 conversions.
#define C0 (BL*DIM/4)      // x     : 1048576 float4
#define C1 (NQKV*DIM/4)    // w_qkv :  786432
#define C2 (DIM*DIM/4)     // w_proj:  262144
__global__ __launch_bounds__(256) void cvt_all(const float* __restrict__ x,
        const float* __restrict__ wq, const float* __restrict__ wp,
        bf16* __restrict__ xb, bf16* __restrict__ wqb, bf16* __restrict__ wpb) {
    int i = blockIdx.x * 256 + threadIdx.x;
    const float* in; bf16* out; int j;
    if (i < C0)            { in = x;  out = xb;  j = i; }
    else if (i < C0 + C1)  { in = wq; out = wqb; j = i - C0; }
    else                   { in = wp; out = wpb; j = i - C0 - C1; }
    float4 f = ((const float4*)in)[j];
    bf16x4 o = { (bf16)f.x, (bf16)f.y, (bf16)f.z, (bf16)f.w };
    ((bf16x4*)out)[j] = o;
}

// QKV GEMM: 128x128 tile, BK=64, XOR-swizzled LDS, operand-swapped MFMA
// (A-op = W rows) -> vectorized Q/K stores, lane-contiguous V stores.
__global__ __launch_bounds__(256, 3) void gemm_qkv(
        const bf16* __restrict__ A, const bf16* __restrict__ W,
        bf16* __restrict__ Qb, bf16* __restrict__ Kb, bf16* __restrict__ VTb) {
    __shared__ bf16 As[128][64];   // x tile, swizzled: LDS[r][c] = glb[r][c^(r&7)]
    __shared__ bf16 Bs[128][64];   // W tile, swizzled
    const int tid = threadIdx.x;
    const int w = tid >> 6, lane = tid & 63, quad = lane >> 4, l16 = lane & 15;
    const int n0 = blockIdx.x * 128, m0 = blockIdx.y * 128;
    const int wm = (w & 1) * 64, wn = (w >> 1) * 64;
    f32x4 acc[4][4] = {};   // acc[tm(n)][tn(m)]
    for (int k0 = 0; k0 < DIM; k0 += 64) {
        #pragma unroll
        for (int i = 0; i < 4; ++i) {        // 1024 chunks per tensor, 4/thread
            int cb = w * 256 + i * 64;       // wave-uniform chunk base
            int gc = cb + lane;
            int r = gc >> 3;
            int cs = (gc & 7) ^ (r & 7);     // swizzled source chunk
            gld_lds16(A + (size_t)(m0 + r) * DIM + k0 + cs*8, &As[0][0] + cb * 8);
            gld_lds16(W + (size_t)(n0 + r) * DIM + k0 + cs*8, &Bs[0][0] + cb * 8);
        }
        __syncthreads();
        #pragma unroll
        for (int kc = 0; kc < 2; ++kc) {
            bf16x8 af[4], bfr[4];
            #pragma unroll
            for (int t = 0; t < 4; ++t) {
                int rw = wn + t*16 + l16;                 // W row (n)
                int cw = (kc*4 + quad) ^ (rw & 7);
                af[t] = *(const bf16x8*)(&Bs[0][0] + rw*64 + cw*8);
                int rx = wm + t*16 + l16;                 // x row (m)
                int cx = (kc*4 + quad) ^ (rx & 7);
                bfr[t] = *(const bf16x8*)(&As[0][0] + rx*64 + cx*8);
            }
            #pragma unroll
            for (int tm = 0; tm < 4; ++tm)
                #pragma unroll
                for (int tn = 0; tn < 4; ++tn)
                    acc[tm][tn] = __builtin_amdgcn_mfma_f32_16x16x32_bf16(
                                      af[tm], bfr[tn], acc[tm][tn], 0, 0, 0);
        }
        __syncthreads();
    }
    // D layout (swapped): row quad*4+r -> n, col l16 -> m
    const int which = n0 >> 10;   // uniform per block
    #pragma unroll
    for (int tm = 0; tm < 4; ++tm) {
        int nb = n0 + wn + tm*16 + quad*4;       // n base for this lane (r=0..3)
        int rem = nb & 1023, h = rem >> 6, db = rem & 63;
        #pragma unroll
        for (int tn = 0; tn < 4; ++tn) {
            int m = m0 + wm + tn*16 + l16;
            int b = m >> 11, l = m & 2047, bh = (b << 4) | h;
            if (which == 0) {
                bf16x4 q4 = { (bf16)(acc[tm][tn][0] * QSCALE),
                              (bf16)(acc[tm][tn][1] * QSCALE),
                              (bf16)(acc[tm][tn][2] * QSCALE),
                              (bf16)(acc[tm][tn][3] * QSCALE) };
                *(bf16x4*)(Qb + ((size_t)bh << 17) + ((size_t)l << 6) + db) = q4;
            } else if (which == 1) {
                bf16x4 k4 = { (bf16)acc[tm][tn][0], (bf16)acc[tm][tn][1],
                              (bf16)acc[tm][tn][2], (bf16)acc[tm][tn][3] };
                *(bf16x4*)(Kb + ((size_t)bh << 17) + ((size_t)l << 6) + db) = k4;
            } else {
                #pragma unroll
                for (int r = 0; r < 4; ++r)   // lanes contiguous in l: 32B chunks
                    VTb[((size_t)bh << 17) + ((size_t)(db + r) << 11) + l] =
                        (bf16)acc[tm][tn][r];
            }
        }
    }
}

// proj: 128(M)x64(N), BK=64, swizzled, operand-swapped -> float4 stores w/ bias.
__global__ __launch_bounds__(256, 3) void gemm_proj(
        const bf16* __restrict__ A, const bf16* __restrict__ W,
        const float* __restrict__ bias, float* __restrict__ out) {
    __shared__ bf16 As[128][64];
    __shared__ bf16 Bs[64][64];
    const int tid = threadIdx.x;
    const int w = tid >> 6, lane = tid & 63, quad = lane >> 4, l16 = lane & 15;
    const int n0 = blockIdx.x * 64, m0 = blockIdx.y * 128;
    const int wm = (w & 1) * 64, wn = (w >> 1) * 32;
    f32x4 acc[2][4] = {};   // acc[tm(n)][tn(m)]
    for (int k0 = 0; k0 < DIM; k0 += 64) {
        #pragma unroll
        for (int i = 0; i < 4; ++i) {        // A: 1024 chunks, 4/thread
            int cb = w * 256 + i * 64;
            int gc = cb + lane;
            int r = gc >> 3;
            int cs = (gc & 7) ^ (r & 7);
            gld_lds16(A + (size_t)(m0 + r) * DIM + k0 + cs*8, &As[0][0] + cb * 8);
        }
        #pragma unroll
        for (int i = 0; i < 2; ++i) {        // B: 512 chunks, 2/thread
            int cb = w * 128 + i * 64;
            int gc = cb + lane;
            int r = gc >> 3;
            int cs = (gc & 7) ^ (r & 7);
            gld_lds16(W + (size_t)(n0 + r) * DIM + k0 + cs*8, &Bs[0][0] + cb * 8);
        }
        __syncthreads();
        #pragma unroll
        for (int kc = 0; kc < 2; ++kc) {
            bf16x8 af[2], bfr[4];
            #pragma unroll
            for (int t = 0; t < 2; ++t) {
                int rw = wn + t*16 + l16;
                int cw = (kc*4 + quad) ^ (rw & 7);
                af[t] = *(const bf16x8*)(&Bs[0][0] + rw*64 + cw*8);
            }
            #pragma unroll
            for (int t = 0; t < 4; ++t) {
                int rx = wm + t*16 + l16;
                int cx = (kc*4 + quad) ^ (rx & 7);
                bfr[t] = *(const bf16x8*)(&As[0][0] + rx*64 + cx*8);
            }
            #pragma unroll
            for (int tm = 0; tm < 2; ++tm)
                #pragma unroll
                for (int tn = 0; tn < 4; ++tn)
                    acc[tm][tn] = __builtin_amdgcn_mfma_f32_16x16x32_bf16(
                                      af[tm], bfr[tn], acc[tm][tn], 0, 0, 0);
        }
        __syncthreads();
    }
    #pragma unroll
    for (int tm = 0; tm < 2; ++tm) {
        int nb = n0 + wn + tm*16 + quad*4;
        float4 b4 = *(const float4*)&bias[nb];
        #pragma unroll
        for (int tn = 0; tn < 4; ++tn) {
            int m = m0 + wm + tn*16 + l16;
            float4 o4 = { acc[tm][tn][0] + b4.x, acc[tm][tn][1] + b4.y,
                          acc[tm][tn][2] + b4.z, acc[tm][tn][3] + b4.w };
            *(float4*)(out + (size_t)m * DIM + nb) = o4;
        }
    }
}

// Flash attention, no max-rescale, FULLY IN-REGISTER, NO LDS, NO BARRIERS.
// S is computed operand-SWAPPED (A = K-frag with permuted row map, B = aq), so
// lane (quad,l16) holds P[q=l16][k = kk*32 + quad*8 + (u*4+r)] -> PV A-fragment
// is lane-local after exp2+pack. K and V fragments are loaded DIRECTLY from
// global to registers: the frag pattern is 16 rows x 64B contiguous chunks
// (every fetched 128B line fully consumed within the iter), all 4 waves of a
// block issue identical addresses so L1 serves the intra-block 4x reuse, and
// per-lane offsets are loop-invariant ints (saddr+voffset, ~zero address VALU).
// Removing LDS kills both barriers and their vmcnt/lgkm full drains -- the
// measured ~3x gap between issue work (~1300 cyc/iter/SIMD) and wall
// (~4900 cyc/iter) was that drain. Pipeline via named register sets with WAR
// ordering: loadK(kt) -> PV(kt-1) [K latency hides under PV] -> loadV(kt)
// [V latency hides under S+exp, consumed next iter] -> S(kt) -> exp2/pack.
__global__ __launch_bounds__(256, 2) void attn(
        const bf16* __restrict__ Qb, const bf16* __restrict__ Kb,
        const bf16* __restrict__ VTb, bf16* __restrict__ AO) {
    const int tid = threadIdx.x;
    const int w = tid >> 6, lane = tid & 63, quad = lane >> 4, l16 = lane & 15;
    // Bijective XCD swizzle (nwg=512, 512%8==0): linear id round-robins XCDs;
    // give each XCD a contiguous bh-major chunk -> 4 heads' K/V per XCD L2.
    const int linear = blockIdx.y * 16 + blockIdx.x;
    const int swz = (linear & 7) * 64 + (linear >> 3);
    const int qt = swz & 15, bh = swz >> 4;
    const bf16* Qg = Qb + ((size_t)bh << 17) + (size_t)(qt * 128) * 64;
    const bf16* Kg = Kb + ((size_t)bh << 17);
    const bf16* Vg = VTb + ((size_t)bh << 17);

    bf16x8 aq[2][2];   // aq[sub][kd]: Q[q=w*32+sub*16+l16][d=kd*32+quad*8+..]
    #pragma unroll
    for (int sub = 0; sub < 2; ++sub)
        #pragma unroll
        for (int kd = 0; kd < 2; ++kd)
            aq[sub][kd] = *(const bf16x8*)(Qg + (size_t)(w*32 + sub*16 + l16) * 64
                                           + kd*32 + quad*8);

    bf16x8 onesf = {};
    if (l16 == 0)
        #pragma unroll
        for (int j = 0; j < 8; ++j) onesf[j] = (bf16)1.0f;

    // Loop-invariant per-lane element offsets for direct global->reg frags.
    int kofs[2][2][2];   // [kk][u][kd]: K[rk][kd*32+quad*8..], permuted rows
    #pragma unroll
    for (int kk = 0; kk < 2; ++kk)
        #pragma unroll
        for (int u = 0; u < 2; ++u)
            #pragma unroll
            for (int kd = 0; kd < 2; ++kd) {
                int rk = kk*32 + ((l16 >> 2) << 3) + u*4 + (l16 & 3);
                kofs[kk][u][kd] = rk*64 + kd*32 + quad*8;
            }
    int vofs[2][4];      // [kk][nt]: VT[nt*16+l16][kk*32+quad*8..]
    #pragma unroll
    for (int kk = 0; kk < 2; ++kk)
        #pragma unroll
        for (int nt = 0; nt < 4; ++nt)
            vofs[kk][nt] = (nt*16 + l16) * 2048 + kk*32 + quad*8;

    f32x4 oacc[2][4] = {};
    f32x4 lacc[2] = {};
    const f32x4 zero4 = {};        // constant C-operand: no per-iter acc init
    bf16x8 ap[2][2];               // P regs: packed iter kt, PV'd iter kt+1
    bf16x8 kf[2][2][2];            // K frags, current iter
    bf16x8 vf[2][4];               // V frags, loaded kt, consumed kt+1

    auto loadK = [&](int kt) {
        const int kb = kt * 4096;  // 64 rows * 64 elems
        #pragma unroll
        for (int kk = 0; kk < 2; ++kk)
            #pragma unroll
            for (int u = 0; u < 2; ++u)
                #pragma unroll
                for (int kd = 0; kd < 2; ++kd)
                    kf[kk][u][kd] =
                        *(const bf16x8*)(Kg + kb + kofs[kk][u][kd]);
    };
    auto loadV = [&](int kt) {
        const int vb = kt * 64;
        #pragma unroll
        for (int kk = 0; kk < 2; ++kk)
            #pragma unroll
            for (int nt = 0; nt < 4; ++nt)
                vf[kk][nt] = *(const bf16x8*)(Vg + vb + vofs[kk][nt]);
    };
    // S^T(kt) from kf, then exp2 -> ap. kd=0 MFMA uses constant zero C-operand.
    auto sphase = [&]() {
        f32x4 s[2][2][2];
        #pragma unroll
        for (int kk = 0; kk < 2; ++kk)
            #pragma unroll
            for (int u = 0; u < 2; ++u)
                #pragma unroll
                for (int sub = 0; sub < 2; ++sub) {
                    s[sub][kk][u] = __builtin_amdgcn_mfma_f32_16x16x32_bf16(
                                        kf[kk][u][0], aq[sub][0], zero4, 0, 0, 0);
                    s[sub][kk][u] = __builtin_amdgcn_mfma_f32_16x16x32_bf16(
                                        kf[kk][u][1], aq[sub][1], s[sub][kk][u],
                                        0, 0, 0);
                }
        #pragma unroll
        for (int sub = 0; sub < 2; ++sub)
            #pragma unroll
            for (int kk = 0; kk < 2; ++kk) {
                bf16x8 p;
                #pragma unroll
                for (int u = 0; u < 2; ++u)
                    #pragma unroll
                    for (int r = 0; r < 4; ++r)
                        p[u*4 + r] = (bf16)exp2f(s[sub][kk][u][r]);
                ap[sub][kk] = p;
            }
    };
    // PV for register P-frags 'ap' against register V-frags 'vf'
    auto pv = [&]() {
        #pragma unroll
        for (int kk = 0; kk < 2; ++kk) {
            #pragma unroll
            for (int nt = 0; nt < 4; ++nt)
                #pragma unroll
                for (int sub = 0; sub < 2; ++sub)
                    oacc[sub][nt] = __builtin_amdgcn_mfma_f32_16x16x32_bf16(
                                        ap[sub][kk], vf[kk][nt], oacc[sub][nt],
                                        0, 0, 0);
            #pragma unroll
            for (int sub = 0; sub < 2; ++sub)
                lacc[sub] = __builtin_amdgcn_mfma_f32_16x16x32_bf16(
                                ap[sub][kk], onesf, lacc[sub], 0, 0, 0);
        }
    };

    // kt = 0 peeled (no PV); then steady-state; then final PV.
    loadK(0);
    loadV(0);
    sphase();
    for (int kt = 1; kt < 32; ++kt) {
        loadK(kt);     // K latency covered by PV below
        pv();          // PV(kt-1): reads vf + ap from last iter
        loadV(kt);     // WAR on vf: issues after pv consumed it; lands by kt+1
        sphase();      // S(kt) -> ap (WAR: after pv consumed ap)
    }
    pv();              // PV(31)

    const int b = bh >> 4, h = bh & 15;
    #pragma unroll
    for (int sub = 0; sub < 2; ++sub)
        #pragma unroll
        for (int r = 0; r < 4; ++r) {
            float l = __shfl(lacc[sub][r], quad * 16, 64);  // col-0 lane of quad
            float inv = 1.0f / l;
            int lq = qt*128 + w*32 + sub*16 + quad*4 + r;
            size_t rowbase = ((size_t)(b * 2048 + lq)) * DIM + h * 64;
            #pragma unroll
            for (int nt = 0; nt < 4; ++nt)
                AO[rowbase + nt*16 + l16] = (bf16)(oacc[sub][nt][r] * inv);
        }
}

extern "C" void kernel_launch(void* const* d_in, const int* in_sizes, int n_in,
                              void* d_out, int out_size, void* d_ws, size_t ws_size,
                              hipStream_t stream) {
    const float* x      = (const float*)d_in[0];
    const float* w_qkv  = (const float*)d_in[1];
    const float* w_proj = (const float*)d_in[2];
    const float* b_proj = (const float*)d_in[3];
    float* out = (float*)d_out;
    char* ws = (char*)d_ws;

    bf16* xb  = (bf16*)(ws);                    // 8 MB
    bf16* wqb = (bf16*)(ws + ( 8u << 20));      // 6 MB
    bf16* wpb = (bf16*)(ws + (14u << 20));      // 2 MB
    bf16* Qb  = (bf16*)(ws + (16u << 20));      // 8 MB [bh][l][d]
    bf16* Kb  = (bf16*)(ws + (24u << 20));      // 8 MB [bh][l][d]
    bf16* VTb = (bf16*)(ws + (32u << 20));      // 8 MB [bh][d][l]
    bf16* AOb = (bf16*)(ws + (40u << 20));      // 8 MB [b*l][h*d]

    cvt_all<<<(C0 + C1 + C2) / 256, 256, 0, stream>>>(x, w_qkv, w_proj, xb, wqb, wpb);
    gemm_qkv<<<dim3(NQKV/128, BL/128), 256, 0, stream>>>(xb, wqb, Qb, Kb, VTb);
    attn<<<dim3(LL/128, BB*NH),        256, 0, stream>>>(Qb, Kb, VTb, AOb);
    gemm_proj<<<dim3(DIM/64, BL/128),  256, 0, stream>>>(AOb, wpb, b_proj, out);
}

// Round 3
// 181.495 us; speedup vs baseline: 1.3495x; 1.3495x over previous
//
#include <hip/hip_runtime.h>

#define DIM 1024
#define NH 16
#define HD 64
#define BB 2
#define LL 2048
#define BL (BB*LL)     // 4096
#define NQKV (3*DIM)   // 3072

typedef __bf16 bf16;
typedef __bf16 bf16x4 __attribute__((ext_vector_type(4)));
typedef __bf16 bf16x8 __attribute__((ext_vector_type(8)));
typedef float  f32x4  __attribute__((ext_vector_type(4)));

// 0.125 * log2(e): fold head-dim scale + base-2 conversion into Q
#define QSCALE 0.1803368801111204f

typedef __attribute__((address_space(3))) unsigned int lds_u32;
typedef __attribute__((address_space(1))) unsigned int glb_u32;

// async global->LDS, 16B per lane. LDS dest = wave-uniform base + lane*16.
__device__ __forceinline__ void gld_lds16(const bf16* g, bf16* l) {
    __builtin_amdgcn_global_load_lds((const glb_u32*)g, (lds_u32*)l, 16, 0, 0);
}

// One kernel for all three fp32->bf16 conversions.
#define C0 (BL*DIM/4)      // x     : 1048576 float4
#define C1 (NQKV*DIM/4)    // w_qkv :  786432
#define C2 (DIM*DIM/4)     // w_proj:  262144
__global__ __launch_bounds__(256) void cvt_all(const float* __restrict__ x,
        const float* __restrict__ wq, const float* __restrict__ wp,
        bf16* __restrict__ xb, bf16* __restrict__ wqb, bf16* __restrict__ wpb) {
    int i = blockIdx.x * 256 + threadIdx.x;
    const float* in; bf16* out; int j;
    if (i < C0)            { in = x;  out = xb;  j = i; }
    else if (i < C0 + C1)  { in = wq; out = wqb; j = i - C0; }
    else                   { in = wp; out = wpb; j = i - C0 - C1; }
    float4 f = ((const float4*)in)[j];
    bf16x4 o = { (bf16)f.x, (bf16)f.y, (bf16)f.z, (bf16)f.w };
    ((bf16x4*)out)[j] = o;
}

// QKV GEMM: 128x128 tile, BK=64, XOR-swizzled LDS, operand-swapped MFMA
// (A-op = W rows) -> vectorized Q/K stores, lane-contiguous V stores.
__global__ __launch_bounds__(256, 3) void gemm_qkv(
        const bf16* __restrict__ A, const bf16* __restrict__ W,
        bf16* __restrict__ Qb, bf16* __restrict__ Kb, bf16* __restrict__ VTb) {
    __shared__ bf16 As[128][64];   // x tile, swizzled: LDS[r][c] = glb[r][c^(r&7)]
    __shared__ bf16 Bs[128][64];   // W tile, swizzled
    const int tid = threadIdx.x;
    const int w = tid >> 6, lane = tid & 63, quad = lane >> 4, l16 = lane & 15;
    const int n0 = blockIdx.x * 128, m0 = blockIdx.y * 128;
    const int wm = (w & 1) * 64, wn = (w >> 1) * 64;
    f32x4 acc[4][4] = {};   // acc[tm(n)][tn(m)]
    for (int k0 = 0; k0 < DIM; k0 += 64) {
        #pragma unroll
        for (int i = 0; i < 4; ++i) {        // 1024 chunks per tensor, 4/thread
            int cb = w * 256 + i * 64;       // wave-uniform chunk base
            int gc = cb + lane;
            int r = gc >> 3;
            int cs = (gc & 7) ^ (r & 7);     // swizzled source chunk
            gld_lds16(A + (size_t)(m0 + r) * DIM + k0 + cs*8, &As[0][0] + cb * 8);
            gld_lds16(W + (size_t)(n0 + r) * DIM + k0 + cs*8, &Bs[0][0] + cb * 8);
        }
        __syncthreads();
        #pragma unroll
        for (int kc = 0; kc < 2; ++kc) {
            bf16x8 af[4], bfr[4];
            #pragma unroll
            for (int t = 0; t < 4; ++t) {
                int rw = wn + t*16 + l16;                 // W row (n)
                int cw = (kc*4 + quad) ^ (rw & 7);
                af[t] = *(const bf16x8*)(&Bs[0][0] + rw*64 + cw*8);
                int rx = wm + t*16 + l16;                 // x row (m)
                int cx = (kc*4 + quad) ^ (rx & 7);
                bfr[t] = *(const bf16x8*)(&As[0][0] + rx*64 + cx*8);
            }
            #pragma unroll
            for (int tm = 0; tm < 4; ++tm)
                #pragma unroll
                for (int tn = 0; tn < 4; ++tn)
                    acc[tm][tn] = __builtin_amdgcn_mfma_f32_16x16x32_bf16(
                                      af[tm], bfr[tn], acc[tm][tn], 0, 0, 0);
        }
        __syncthreads();
    }
    // D layout (swapped): row quad*4+r -> n, col l16 -> m
    const int which = n0 >> 10;   // uniform per block
    #pragma unroll
    for (int tm = 0; tm < 4; ++tm) {
        int nb = n0 + wn + tm*16 + quad*4;       // n base for this lane (r=0..3)
        int rem = nb & 1023, h = rem >> 6, db = rem & 63;
        #pragma unroll
        for (int tn = 0; tn < 4; ++tn) {
            int m = m0 + wm + tn*16 + l16;
            int b = m >> 11, l = m & 2047, bh = (b << 4) | h;
            if (which == 0) {
                bf16x4 q4 = { (bf16)(acc[tm][tn][0] * QSCALE),
                              (bf16)(acc[tm][tn][1] * QSCALE),
                              (bf16)(acc[tm][tn][2] * QSCALE),
                              (bf16)(acc[tm][tn][3] * QSCALE) };
                *(bf16x4*)(Qb + ((size_t)bh << 17) + ((size_t)l << 6) + db) = q4;
            } else if (which == 1) {
                bf16x4 k4 = { (bf16)acc[tm][tn][0], (bf16)acc[tm][tn][1],
                              (bf16)acc[tm][tn][2], (bf16)acc[tm][tn][3] };
                *(bf16x4*)(Kb + ((size_t)bh << 17) + ((size_t)l << 6) + db) = k4;
            } else {
                #pragma unroll
                for (int r = 0; r < 4; ++r)   // lanes contiguous in l: 32B chunks
                    VTb[((size_t)bh << 17) + ((size_t)(db + r) << 11) + l] =
                        (bf16)acc[tm][tn][r];
            }
        }
    }
}

// proj: 128(M)x64(N), BK=64, swizzled, operand-swapped -> float4 stores w/ bias.
__global__ __launch_bounds__(256, 3) void gemm_proj(
        const bf16* __restrict__ A, const bf16* __restrict__ W,
        const float* __restrict__ bias, float* __restrict__ out) {
    __shared__ bf16 As[128][64];
    __shared__ bf16 Bs[64][64];
    const int tid = threadIdx.x;
    const int w = tid >> 6, lane = tid & 63, quad = lane >> 4, l16 = lane & 15;
    const int n0 = blockIdx.x * 64, m0 = blockIdx.y * 128;
    const int wm = (w & 1) * 64, wn = (w >> 1) * 32;
    f32x4 acc[2][4] = {};   // acc[tm(n)][tn(m)]
    for (int k0 = 0; k0 < DIM; k0 += 64) {
        #pragma unroll
        for (int i = 0; i < 4; ++i) {        // A: 1024 chunks, 4/thread
            int cb = w * 256 + i * 64;
            int gc = cb + lane;
            int r = gc >> 3;
            int cs = (gc & 7) ^ (r & 7);
            gld_lds16(A + (size_t)(m0 + r) * DIM + k0 + cs*8, &As[0][0] + cb * 8);
        }
        #pragma unroll
        for (int i = 0; i < 2; ++i) {        // B: 512 chunks, 2/thread
            int cb = w * 128 + i * 64;
            int gc = cb + lane;
            int r = gc >> 3;
            int cs = (gc & 7) ^ (r & 7);
            gld_lds16(W + (size_t)(n0 + r) * DIM + k0 + cs*8, &Bs[0][0] + cb * 8);
        }
        __syncthreads();
        #pragma unroll
        for (int kc = 0; kc < 2; ++kc) {
            bf16x8 af[2], bfr[4];
            #pragma unroll
            for (int t = 0; t < 2; ++t) {
                int rw = wn + t*16 + l16;
                int cw = (kc*4 + quad) ^ (rw & 7);
                af[t] = *(const bf16x8*)(&Bs[0][0] + rw*64 + cw*8);
            }
            #pragma unroll
            for (int t = 0; t < 4; ++t) {
                int rx = wm + t*16 + l16;
                int cx = (kc*4 + quad) ^ (rx & 7);
                bfr[t] = *(const bf16x8*)(&As[0][0] + rx*64 + cx*8);
            }
            #pragma unroll
            for (int tm = 0; tm < 2; ++tm)
                #pragma unroll
                for (int tn = 0; tn < 4; ++tn)
                    acc[tm][tn] = __builtin_amdgcn_mfma_f32_16x16x32_bf16(
                                      af[tm], bfr[tn], acc[tm][tn], 0, 0, 0);
        }
        __syncthreads();
    }
    #pragma unroll
    for (int tm = 0; tm < 2; ++tm) {
        int nb = n0 + wn + tm*16 + quad*4;
        float4 b4 = *(const float4*)&bias[nb];
        #pragma unroll
        for (int tn = 0; tn < 4; ++tn) {
            int m = m0 + wm + tn*16 + l16;
            float4 o4 = { acc[tm][tn][0] + b4.x, acc[tm][tn][1] + b4.y,
                          acc[tm][tn][2] + b4.z, acc[tm][tn][3] + b4.w };
            *(float4*)(out + (size_t)m * DIM + nb) = o4;
        }
    }
}

// Flash attention, no max-rescale, IN-REGISTER P (R1 structure), now with
// QBLK=256 / 8 waves / kv-SPLIT: waves = 4 q-quarters x 2 kv-halves. Each wave
// reads only its kv-half of the K and V tiles -> 8 ds_read_b128/wave/iter
// instead of 16: total LDS traffic HALVES for the same FLOPs (the 4x cross-
// wave tile-read redundancy was the largest pipe load in R1). Staging per CU
// also halves (one block/CU stages 16KB/iter). Fragment layouts identical to
// R1 with kk->kvh. O and l are partial over kv-halves; a one-time LDS combine
// (wave w+4 -> wave w) runs after the loop, reusing the staging LDS.
// XCD swizzle: 4 heads per XCD -> 2MB K/V L2-resident, 8 q-blocks co-resident.
__global__ __launch_bounds__(512, 2) void attn(
        const bf16* __restrict__ Qb, const bf16* __restrict__ Kb,
        const bf16* __restrict__ VTb, bf16* __restrict__ AO) {
    __shared__ __align__(16) char smem[33280];   // 2x8KB K + 2x8KB V; epilogue
    bf16* KsP  = (bf16*)smem;                    //   reuses it as Ored/Lred
    bf16* VTsP = KsP + 8192;
    const int tid = threadIdx.x;
    const int w = tid >> 6, lane = tid & 63, quad = lane >> 4, l16 = lane & 15;
    const int qw = w & 3, kvh = w >> 2;          // q-quarter, kv-half
    // Bijective XCD swizzle (nwg=256, 256%8==0): XCD x gets bh in [4x, 4x+3].
    const int linear = blockIdx.y * 8 + blockIdx.x;
    const int swz = (linear & 7) * 32 + (linear >> 3);
    const int qt = swz & 7, bh = swz >> 3;
    const bf16* Qg = Qb + ((size_t)bh << 17) + (size_t)(qt * 256) * 64;
    const bf16* Kg = Kb + ((size_t)bh << 17);
    const bf16* Vg = VTb + ((size_t)bh << 17);

    bf16x8 aq[4][2];   // aq[sub][kd]: Q[q=qw*64+sub*16+l16][d=kd*32+quad*8+..]
    #pragma unroll
    for (int sub = 0; sub < 4; ++sub)
        #pragma unroll
        for (int kd = 0; kd < 2; ++kd)
            aq[sub][kd] = *(const bf16x8*)(Qg + (size_t)(qw*64 + sub*16 + l16) * 64
                                           + kd*32 + quad*8);

    bf16x8 onesf = {};
    if (l16 == 0)
        #pragma unroll
        for (int j = 0; j < 8; ++j) onesf[j] = (bf16)1.0f;

    f32x4 oacc[4][4] = {};         // [sub][nt]: O[q=sub*16+quad*4+r][d=nt*16+l16]
    f32x4 lacc[4] = {};            // row-sums, valid at l16==0 lanes
    const f32x4 zero4 = {};
    bf16x8 ap[4];                  // P regs: packed iter kt, PV'd iter kt+1

    // 512 threads stage one 16B chunk each: full 64x64 tile per tensor.
    auto stageK = [&](int kt, int buf) {
        int r = tid >> 3;
        int cs = (tid & 7) ^ (r & 7) ^ ((r >> 3) & 7) ^ ((r & 1) << 2);  // fK
        gld_lds16(Kg + (size_t)(kt*64 + r) * 64 + cs*8, KsP + buf*4096 + tid*8);
    };
    auto stageV = [&](int kt, int buf) {
        int r = tid >> 3;
        int cs = (tid & 7) ^ (r & 7) ^ ((r >> 3) & 7);                   // fV
        gld_lds16(Vg + (size_t)r * 2048 + kt*64 + cs*8, VTsP + buf*4096 + tid*8);
    };
    // PV for register P-frags 'ap' (this wave's kv-half) against VTs[pbuf]
    auto pv = [&](int pbuf) {
        #pragma unroll
        for (int nt = 0; nt < 4; ++nt) {
            int row = nt*16 + l16;                      // d-dim row of VT
            int cp = (kvh*4 + quad) ^ (row & 7) ^ ((row >> 3) & 7);
            bf16x8 bv = *(const bf16x8*)(VTsP + pbuf*4096 + row*64 + cp*8);
            #pragma unroll
            for (int sub = 0; sub < 4; ++sub)
                oacc[sub][nt] = __builtin_amdgcn_mfma_f32_16x16x32_bf16(
                                    ap[sub], bv, oacc[sub][nt], 0, 0, 0);
        }
        #pragma unroll
        for (int sub = 0; sub < 4; ++sub)
            lacc[sub] = __builtin_amdgcn_mfma_f32_16x16x32_bf16(
                            ap[sub], onesf, lacc[sub], 0, 0, 0);
    };

    // One pipeline step. Barrier: K(kt)+V(kt-1) staging landed (loads were
    // issued a full iteration ago); all waves' reads of the buffers about to
    // be overwritten completed last iter.
    auto body = [&](int kt, int cur) {
        __syncthreads();
        if (kt < 31) stageK(kt + 1, cur ^ 1);
        stageV(kt, cur);                      // read at iter kt+1 (or epilogue)

        // PV(kt-1): register P (old ap) + VTs[cur^1]
        if (kt > 0) pv(cur ^ 1);

        // S^T(kt) from Ks[cur]: A = K-frag (permuted rows, this kv-half), B=aq
        f32x4 s[4][2];   // [sub][u]
        #pragma unroll
        for (int u = 0; u < 2; ++u) {
            bf16x8 kf0, kf1;
            int rk = kvh*32 + ((l16 >> 2) << 3) + u*4 + (l16 & 3);
            int f = (rk & 7) ^ ((rk >> 3) & 7) ^ ((rk & 1) << 2);
            kf0 = *(const bf16x8*)(KsP + cur*4096 + rk*64 + ((0*4 + quad) ^ f)*8);
            kf1 = *(const bf16x8*)(KsP + cur*4096 + rk*64 + ((1*4 + quad) ^ f)*8);
            #pragma unroll
            for (int sub = 0; sub < 4; ++sub) {
                s[sub][u] = __builtin_amdgcn_mfma_f32_16x16x32_bf16(
                                kf0, aq[sub][0], zero4, 0, 0, 0);
                s[sub][u] = __builtin_amdgcn_mfma_f32_16x16x32_bf16(
                                kf1, aq[sub][1], s[sub][u], 0, 0, 0);
            }
        }

        // exp2 + pack P(kt) into registers; consumed next iteration.
        // Lane (quad,l16) holds P[q=l16][kv = kvh*32 + quad*8 + u*4 + r].
        #pragma unroll
        for (int sub = 0; sub < 4; ++sub) {
            bf16x8 p;
            #pragma unroll
            for (int u = 0; u < 2; ++u)
                #pragma unroll
                for (int r = 0; r < 4; ++r)
                    p[u*4 + r] = (bf16)exp2f(s[sub][u][r]);
            ap[sub] = p;
        }
    };

    stageK(0, 0);
    for (int kt2 = 0; kt2 < 32; kt2 += 2) {
        body(kt2,     0);
        body(kt2 + 1, 1);
    }
    __syncthreads();   // V(31) staging landed for all waves
    pv(1);             // final PV(31)

    // Combine kv-halves: wave w+4 adds into wave w via LDS (staging reuse).
    // Two rounds of 2 writer-waves (2 x 16KB = 32KB fits the staging space).
    float* OredF = (float*)smem;            // [slot2][sub4][row16][d64]
    float* LredF = (float*)(smem + 32768);  // [slot2][sub4][row16]
    const int b = bh >> 4, h = bh & 15;
    #pragma unroll
    for (int t = 0; t < 2; ++t) {
        __syncthreads();
        if (kvh == 1 && (qw >> 1) == t) {
            int slot = qw & 1;
            #pragma unroll
            for (int sub = 0; sub < 4; ++sub)
                #pragma unroll
                for (int nt = 0; nt < 4; ++nt)
                    #pragma unroll
                    for (int r = 0; r < 4; ++r)
                        OredF[((slot*4 + sub)*16 + quad*4 + r)*64 + nt*16 + l16]
                            = oacc[sub][nt][r];
            if (l16 == 0)
                #pragma unroll
                for (int sub = 0; sub < 4; ++sub)
                    #pragma unroll
                    for (int r = 0; r < 4; ++r)
                        LredF[(slot*4 + sub)*16 + quad*4 + r] = lacc[sub][r];
        }
        __syncthreads();
        if (kvh == 0 && (qw >> 1) == t) {
            int slot = qw & 1;
            #pragma unroll
            for (int sub = 0; sub < 4; ++sub)
                #pragma unroll
                for (int nt = 0; nt < 4; ++nt)
                    #pragma unroll
                    for (int r = 0; r < 4; ++r)
                        oacc[sub][nt][r] +=
                            OredF[((slot*4 + sub)*16 + quad*4 + r)*64 + nt*16 + l16];
            if (l16 == 0)
                #pragma unroll
                for (int sub = 0; sub < 4; ++sub)
                    #pragma unroll
                    for (int r = 0; r < 4; ++r)
                        lacc[sub][r] += LredF[(slot*4 + sub)*16 + quad*4 + r];
            #pragma unroll
            for (int sub = 0; sub < 4; ++sub)
                #pragma unroll
                for (int r = 0; r < 4; ++r) {
                    float l = __shfl(lacc[sub][r], quad * 16, 64);
                    float inv = 1.0f / l;
                    int lq = qt*256 + qw*64 + sub*16 + quad*4 + r;
                    size_t rowbase = ((size_t)(b * 2048 + lq)) * DIM + h * 64;
                    #pragma unroll
                    for (int nt = 0; nt < 4; ++nt)
                        AO[rowbase + nt*16 + l16] = (bf16)(oacc[sub][nt][r] * inv);
                }
        }
    }
}

extern "C" void kernel_launch(void* const* d_in, const int* in_sizes, int n_in,
                              void* d_out, int out_size, void* d_ws, size_t ws_size,
                              hipStream_t stream) {
    const float* x      = (const float*)d_in[0];
    const float* w_qkv  = (const float*)d_in[1];
    const float* w_proj = (const float*)d_in[2];
    const float* b_proj = (const float*)d_in[3];
    float* out = (float*)d_out;
    char* ws = (char*)d_ws;

    bf16* xb  = (bf16*)(ws);                    // 8 MB
    bf16* wqb = (bf16*)(ws + ( 8u << 20));      // 6 MB
    bf16* wpb = (bf16*)(ws + (14u << 20));      // 2 MB
    bf16* Qb  = (bf16*)(ws + (16u << 20));      // 8 MB [bh][l][d]
    bf16* Kb  = (bf16*)(ws + (24u << 20));      // 8 MB [bh][l][d]
    bf16* VTb = (bf16*)(ws + (32u << 20));      // 8 MB [bh][d][l]
    bf16* AOb = (bf16*)(ws + (40u << 20));      // 8 MB [b*l][h*d]

    cvt_all<<<(C0 + C1 + C2) / 256, 256, 0, stream>>>(x, w_qkv, w_proj, xb, wqb, wpb);
    gemm_qkv<<<dim3(NQKV/128, BL/128), 256, 0, stream>>>(xb, wqb, Qb, Kb, VTb);
    attn<<<dim3(LL/256, BB*NH),        512, 0, stream>>>(Qb, Kb, VTb, AOb);
    gemm_proj<<<dim3(DIM/64, BL/128),  256, 0, stream>>>(AOb, wpb, b_proj, out);
}

// Round 4
// 166.707 us; speedup vs baseline: 1.4692x; 1.0887x over previous
//
#include <hip/hip_runtime.h>

#define DIM 1024
#define NH 16
#define HD 64
#define BB 2
#define LL 2048
#define BL (BB*LL)     // 4096
#define NQKV (3*DIM)   // 3072

typedef __bf16 bf16;
typedef __bf16 bf16x4 __attribute__((ext_vector_type(4)));
typedef __bf16 bf16x8 __attribute__((ext_vector_type(8)));
typedef float  f32x4  __attribute__((ext_vector_type(4)));

// 0.125 * log2(e): fold head-dim scale + base-2 conversion into Q
#define QSCALE 0.1803368801111204f

typedef __attribute__((address_space(3))) unsigned int lds_u32;
typedef __attribute__((address_space(1))) unsigned int glb_u32;

// async global->LDS, 16B per lane. LDS dest = wave-uniform base + lane*16.
__device__ __forceinline__ void gld_lds16(const bf16* g, bf16* l) {
    __builtin_amdgcn_global_load_lds((const glb_u32*)g, (lds_u32*)l, 16, 0, 0);
}

// One kernel for all three fp32->bf16 conversions.
#define C0 (BL*DIM/4)      // x     : 1048576 float4
#define C1 (NQKV*DIM/4)    // w_qkv :  786432
#define C2 (DIM*DIM/4)     // w_proj:  262144
__global__ __launch_bounds__(256) void cvt_all(const float* __restrict__ x,
        const float* __restrict__ wq, const float* __restrict__ wp,
        bf16* __restrict__ xb, bf16* __restrict__ wqb, bf16* __restrict__ wpb) {
    int i = blockIdx.x * 256 + threadIdx.x;
    const float* in; bf16* out; int j;
    if (i < C0)            { in = x;  out = xb;  j = i; }
    else if (i < C0 + C1)  { in = wq; out = wqb; j = i - C0; }
    else                   { in = wp; out = wpb; j = i - C0 - C1; }
    float4 f = ((const float4*)in)[j];
    bf16x4 o = { (bf16)f.x, (bf16)f.y, (bf16)f.z, (bf16)f.w };
    ((bf16x4*)out)[j] = o;
}

// QKV GEMM: 128x128 tile, BK=64, XOR-swizzled LDS, operand-swapped MFMA
// (A-op = W rows) -> vectorized Q/K stores, lane-contiguous V stores.
__global__ __launch_bounds__(256, 3) void gemm_qkv(
        const bf16* __restrict__ A, const bf16* __restrict__ W,
        bf16* __restrict__ Qb, bf16* __restrict__ Kb, bf16* __restrict__ VTb) {
    __shared__ bf16 As[128][64];   // x tile, swizzled: LDS[r][c] = glb[r][c^(r&7)]
    __shared__ bf16 Bs[128][64];   // W tile, swizzled
    const int tid = threadIdx.x;
    const int w = tid >> 6, lane = tid & 63, quad = lane >> 4, l16 = lane & 15;
    const int n0 = blockIdx.x * 128, m0 = blockIdx.y * 128;
    const int wm = (w & 1) * 64, wn = (w >> 1) * 64;
    f32x4 acc[4][4] = {};   // acc[tm(n)][tn(m)]
    for (int k0 = 0; k0 < DIM; k0 += 64) {
        #pragma unroll
        for (int i = 0; i < 4; ++i) {        // 1024 chunks per tensor, 4/thread
            int cb = w * 256 + i * 64;       // wave-uniform chunk base
            int gc = cb + lane;
            int r = gc >> 3;
            int cs = (gc & 7) ^ (r & 7);     // swizzled source chunk
            gld_lds16(A + (size_t)(m0 + r) * DIM + k0 + cs*8, &As[0][0] + cb * 8);
            gld_lds16(W + (size_t)(n0 + r) * DIM + k0 + cs*8, &Bs[0][0] + cb * 8);
        }
        __syncthreads();
        #pragma unroll
        for (int kc = 0; kc < 2; ++kc) {
            bf16x8 af[4], bfr[4];
            #pragma unroll
            for (int t = 0; t < 4; ++t) {
                int rw = wn + t*16 + l16;                 // W row (n)
                int cw = (kc*4 + quad) ^ (rw & 7);
                af[t] = *(const bf16x8*)(&Bs[0][0] + rw*64 + cw*8);
                int rx = wm + t*16 + l16;                 // x row (m)
                int cx = (kc*4 + quad) ^ (rx & 7);
                bfr[t] = *(const bf16x8*)(&As[0][0] + rx*64 + cx*8);
            }
            #pragma unroll
            for (int tm = 0; tm < 4; ++tm)
                #pragma unroll
                for (int tn = 0; tn < 4; ++tn)
                    acc[tm][tn] = __builtin_amdgcn_mfma_f32_16x16x32_bf16(
                                      af[tm], bfr[tn], acc[tm][tn], 0, 0, 0);
        }
        __syncthreads();
    }
    // D layout (swapped): row quad*4+r -> n, col l16 -> m
    const int which = n0 >> 10;   // uniform per block
    #pragma unroll
    for (int tm = 0; tm < 4; ++tm) {
        int nb = n0 + wn + tm*16 + quad*4;       // n base for this lane (r=0..3)
        int rem = nb & 1023, h = rem >> 6, db = rem & 63;
        #pragma unroll
        for (int tn = 0; tn < 4; ++tn) {
            int m = m0 + wm + tn*16 + l16;
            int b = m >> 11, l = m & 2047, bh = (b << 4) | h;
            if (which == 0) {
                bf16x4 q4 = { (bf16)(acc[tm][tn][0] * QSCALE),
                              (bf16)(acc[tm][tn][1] * QSCALE),
                              (bf16)(acc[tm][tn][2] * QSCALE),
                              (bf16)(acc[tm][tn][3] * QSCALE) };
                *(bf16x4*)(Qb + ((size_t)bh << 17) + ((size_t)l << 6) + db) = q4;
            } else if (which == 1) {
                bf16x4 k4 = { (bf16)acc[tm][tn][0], (bf16)acc[tm][tn][1],
                              (bf16)acc[tm][tn][2], (bf16)acc[tm][tn][3] };
                *(bf16x4*)(Kb + ((size_t)bh << 17) + ((size_t)l << 6) + db) = k4;
            } else {
                #pragma unroll
                for (int r = 0; r < 4; ++r)   // lanes contiguous in l: 32B chunks
                    VTb[((size_t)bh << 17) + ((size_t)(db + r) << 11) + l] =
                        (bf16)acc[tm][tn][r];
            }
        }
    }
}

// proj: 128(M)x64(N), BK=64, swizzled, operand-swapped -> float4 stores w/ bias.
__global__ __launch_bounds__(256, 3) void gemm_proj(
        const bf16* __restrict__ A, const bf16* __restrict__ W,
        const float* __restrict__ bias, float* __restrict__ out) {
    __shared__ bf16 As[128][64];
    __shared__ bf16 Bs[64][64];
    const int tid = threadIdx.x;
    const int w = tid >> 6, lane = tid & 63, quad = lane >> 4, l16 = lane & 15;
    const int n0 = blockIdx.x * 64, m0 = blockIdx.y * 128;
    const int wm = (w & 1) * 64, wn = (w >> 1) * 32;
    f32x4 acc[2][4] = {};   // acc[tm(n)][tn(m)]
    for (int k0 = 0; k0 < DIM; k0 += 64) {
        #pragma unroll
        for (int i = 0; i < 4; ++i) {        // A: 1024 chunks, 4/thread
            int cb = w * 256 + i * 64;
            int gc = cb + lane;
            int r = gc >> 3;
            int cs = (gc & 7) ^ (r & 7);
            gld_lds16(A + (size_t)(m0 + r) * DIM + k0 + cs*8, &As[0][0] + cb * 8);
        }
        #pragma unroll
        for (int i = 0; i < 2; ++i) {        // B: 512 chunks, 2/thread
            int cb = w * 128 + i * 64;
            int gc = cb + lane;
            int r = gc >> 3;
            int cs = (gc & 7) ^ (r & 7);
            gld_lds16(W + (size_t)(n0 + r) * DIM + k0 + cs*8, &Bs[0][0] + cb * 8);
        }
        __syncthreads();
        #pragma unroll
        for (int kc = 0; kc < 2; ++kc) {
            bf16x8 af[2], bfr[4];
            #pragma unroll
            for (int t = 0; t < 2; ++t) {
                int rw = wn + t*16 + l16;
                int cw = (kc*4 + quad) ^ (rw & 7);
                af[t] = *(const bf16x8*)(&Bs[0][0] + rw*64 + cw*8);
            }
            #pragma unroll
            for (int t = 0; t < 4; ++t) {
                int rx = wm + t*16 + l16;
                int cx = (kc*4 + quad) ^ (rx & 7);
                bfr[t] = *(const bf16x8*)(&As[0][0] + rx*64 + cx*8);
            }
            #pragma unroll
            for (int tm = 0; tm < 2; ++tm)
                #pragma unroll
                for (int tn = 0; tn < 4; ++tn)
                    acc[tm][tn] = __builtin_amdgcn_mfma_f32_16x16x32_bf16(
                                      af[tm], bfr[tn], acc[tm][tn], 0, 0, 0);
        }
        __syncthreads();
    }
    #pragma unroll
    for (int tm = 0; tm < 2; ++tm) {
        int nb = n0 + wn + tm*16 + quad*4;
        float4 b4 = *(const float4*)&bias[nb];
        #pragma unroll
        for (int tn = 0; tn < 4; ++tn) {
            int m = m0 + wm + tn*16 + l16;
            float4 o4 = { acc[tm][tn][0] + b4.x, acc[tm][tn][1] + b4.y,
                          acc[tm][tn][2] + b4.z, acc[tm][tn][3] + b4.w };
            *(float4*)(out + (size_t)m * DIM + nb) = o4;
        }
    }
}

// Flash attention, QBLK=256 / 8 waves / kv-split (R3 structure), with two
// VALU fixes found by issue-count arithmetic (VALUBusy pinned at 50% across
// R0/R1/R3 while every memory-side fix bounced):
//  1. exp2f() -> __builtin_amdgcn_exp2f: ocml exp2 is ~10 VALU ops per call
//     (range checks around v_exp_f32); 32 calls/wave/iter made softmax-exp
//     ~half of all VALU issue. Raw v_exp_f32 is 1 issue slot; P is rounded to
//     bf16 right after, so the ~1-ulp difference is noise.
//  2. s_setprio(1) around the S and PV MFMA clusters (T5): staging/exp waves
//     yield issue slots to MFMA-entering waves.
__global__ __launch_bounds__(512, 2) void attn(
        const bf16* __restrict__ Qb, const bf16* __restrict__ Kb,
        const bf16* __restrict__ VTb, bf16* __restrict__ AO) {
    __shared__ __align__(16) char smem[33280];   // 2x8KB K + 2x8KB V; epilogue
    bf16* KsP  = (bf16*)smem;                    //   reuses it as Ored/Lred
    bf16* VTsP = KsP + 8192;
    const int tid = threadIdx.x;
    const int w = tid >> 6, lane = tid & 63, quad = lane >> 4, l16 = lane & 15;
    const int qw = w & 3, kvh = w >> 2;          // q-quarter, kv-half
    // Bijective XCD swizzle (nwg=256, 256%8==0): XCD x gets bh in [4x, 4x+3].
    const int linear = blockIdx.y * 8 + blockIdx.x;
    const int swz = (linear & 7) * 32 + (linear >> 3);
    const int qt = swz & 7, bh = swz >> 3;
    const bf16* Qg = Qb + ((size_t)bh << 17) + (size_t)(qt * 256) * 64;
    const bf16* Kg = Kb + ((size_t)bh << 17);
    const bf16* Vg = VTb + ((size_t)bh << 17);

    bf16x8 aq[4][2];   // aq[sub][kd]: Q[q=qw*64+sub*16+l16][d=kd*32+quad*8+..]
    #pragma unroll
    for (int sub = 0; sub < 4; ++sub)
        #pragma unroll
        for (int kd = 0; kd < 2; ++kd)
            aq[sub][kd] = *(const bf16x8*)(Qg + (size_t)(qw*64 + sub*16 + l16) * 64
                                           + kd*32 + quad*8);

    bf16x8 onesf = {};
    if (l16 == 0)
        #pragma unroll
        for (int j = 0; j < 8; ++j) onesf[j] = (bf16)1.0f;

    f32x4 oacc[4][4] = {};         // [sub][nt]: O[q=sub*16+quad*4+r][d=nt*16+l16]
    f32x4 lacc[4] = {};            // row-sums, valid at l16==0 lanes
    const f32x4 zero4 = {};
    bf16x8 ap[4];                  // P regs: packed iter kt, PV'd iter kt+1

    // 512 threads stage one 16B chunk each: full 64x64 tile per tensor.
    auto stageK = [&](int kt, int buf) {
        int r = tid >> 3;
        int cs = (tid & 7) ^ (r & 7) ^ ((r >> 3) & 7) ^ ((r & 1) << 2);  // fK
        gld_lds16(Kg + (size_t)(kt*64 + r) * 64 + cs*8, KsP + buf*4096 + tid*8);
    };
    auto stageV = [&](int kt, int buf) {
        int r = tid >> 3;
        int cs = (tid & 7) ^ (r & 7) ^ ((r >> 3) & 7);                   // fV
        gld_lds16(Vg + (size_t)r * 2048 + kt*64 + cs*8, VTsP + buf*4096 + tid*8);
    };
    // PV for register P-frags 'ap' (this wave's kv-half) against VTs[pbuf]
    auto pv = [&](int pbuf) {
        __builtin_amdgcn_s_setprio(1);
        #pragma unroll
        for (int nt = 0; nt < 4; ++nt) {
            int row = nt*16 + l16;                      // d-dim row of VT
            int cp = (kvh*4 + quad) ^ (row & 7) ^ ((row >> 3) & 7);
            bf16x8 bv = *(const bf16x8*)(VTsP + pbuf*4096 + row*64 + cp*8);
            #pragma unroll
            for (int sub = 0; sub < 4; ++sub)
                oacc[sub][nt] = __builtin_amdgcn_mfma_f32_16x16x32_bf16(
                                    ap[sub], bv, oacc[sub][nt], 0, 0, 0);
        }
        #pragma unroll
        for (int sub = 0; sub < 4; ++sub)
            lacc[sub] = __builtin_amdgcn_mfma_f32_16x16x32_bf16(
                            ap[sub], onesf, lacc[sub], 0, 0, 0);
        __builtin_amdgcn_s_setprio(0);
    };

    // One pipeline step. Barrier: K(kt)+V(kt-1) staging landed (loads were
    // issued a full iteration ago); all waves' reads of the buffers about to
    // be overwritten completed last iter.
    auto body = [&](int kt, int cur) {
        __syncthreads();
        if (kt < 31) stageK(kt + 1, cur ^ 1);
        stageV(kt, cur);                      // read at iter kt+1 (or epilogue)

        // PV(kt-1): register P (old ap) + VTs[cur^1]
        if (kt > 0) pv(cur ^ 1);

        // S^T(kt) from Ks[cur]: A = K-frag (permuted rows, this kv-half), B=aq
        f32x4 s[4][2];   // [sub][u]
        __builtin_amdgcn_s_setprio(1);
        #pragma unroll
        for (int u = 0; u < 2; ++u) {
            bf16x8 kf0, kf1;
            int rk = kvh*32 + ((l16 >> 2) << 3) + u*4 + (l16 & 3);
            int f = (rk & 7) ^ ((rk >> 3) & 7) ^ ((rk & 1) << 2);
            kf0 = *(const bf16x8*)(KsP + cur*4096 + rk*64 + ((0*4 + quad) ^ f)*8);
            kf1 = *(const bf16x8*)(KsP + cur*4096 + rk*64 + ((1*4 + quad) ^ f)*8);
            #pragma unroll
            for (int sub = 0; sub < 4; ++sub) {
                s[sub][u] = __builtin_amdgcn_mfma_f32_16x16x32_bf16(
                                kf0, aq[sub][0], zero4, 0, 0, 0);
                s[sub][u] = __builtin_amdgcn_mfma_f32_16x16x32_bf16(
                                kf1, aq[sub][1], s[sub][u], 0, 0, 0);
            }
        }
        __builtin_amdgcn_s_setprio(0);

        // exp2 + pack P(kt) into registers; consumed next iteration.
        // Lane (quad,l16) holds P[q=l16][kv = kvh*32 + quad*8 + u*4 + r].
        #pragma unroll
        for (int sub = 0; sub < 4; ++sub) {
            bf16x8 p;
            #pragma unroll
            for (int u = 0; u < 2; ++u)
                #pragma unroll
                for (int r = 0; r < 4; ++r)
                    p[u*4 + r] = (bf16)__builtin_amdgcn_exp2f(s[sub][u][r]);
            ap[sub] = p;
        }
    };

    stageK(0, 0);
    for (int kt2 = 0; kt2 < 32; kt2 += 2) {
        body(kt2,     0);
        body(kt2 + 1, 1);
    }
    __syncthreads();   // V(31) staging landed for all waves
    pv(1);             // final PV(31)

    // Combine kv-halves: wave w+4 adds into wave w via LDS (staging reuse).
    // Two rounds of 2 writer-waves (2 x 16KB = 32KB fits the staging space).
    float* OredF = (float*)smem;            // [slot2][sub4][row16][d64]
    float* LredF = (float*)(smem + 32768);  // [slot2][sub4][row16]
    const int b = bh >> 4, h = bh & 15;
    #pragma unroll
    for (int t = 0; t < 2; ++t) {
        __syncthreads();
        if (kvh == 1 && (qw >> 1) == t) {
            int slot = qw & 1;
            #pragma unroll
            for (int sub = 0; sub < 4; ++sub)
                #pragma unroll
                for (int nt = 0; nt < 4; ++nt)
                    #pragma unroll
                    for (int r = 0; r < 4; ++r)
                        OredF[((slot*4 + sub)*16 + quad*4 + r)*64 + nt*16 + l16]
                            = oacc[sub][nt][r];
            if (l16 == 0)
                #pragma unroll
                for (int sub = 0; sub < 4; ++sub)
                    #pragma unroll
                    for (int r = 0; r < 4; ++r)
                        LredF[(slot*4 + sub)*16 + quad*4 + r] = lacc[sub][r];
        }
        __syncthreads();
        if (kvh == 0 && (qw >> 1) == t) {
            int slot = qw & 1;
            #pragma unroll
            for (int sub = 0; sub < 4; ++sub)
                #pragma unroll
                for (int nt = 0; nt < 4; ++nt)
                    #pragma unroll
                    for (int r = 0; r < 4; ++r)
                        oacc[sub][nt][r] +=
                            OredF[((slot*4 + sub)*16 + quad*4 + r)*64 + nt*16 + l16];
            if (l16 == 0)
                #pragma unroll
                for (int sub = 0; sub < 4; ++sub)
                    #pragma unroll
                    for (int r = 0; r < 4; ++r)
                        lacc[sub][r] += LredF[(slot*4 + sub)*16 + quad*4 + r];
            #pragma unroll
            for (int sub = 0; sub < 4; ++sub)
                #pragma unroll
                for (int r = 0; r < 4; ++r) {
                    float l = __shfl(lacc[sub][r], quad * 16, 64);
                    float inv = 1.0f / l;
                    int lq = qt*256 + qw*64 + sub*16 + quad*4 + r;
                    size_t rowbase = ((size_t)(b * 2048 + lq)) * DIM + h * 64;
                    #pragma unroll
                    for (int nt = 0; nt < 4; ++nt)
                        AO[rowbase + nt*16 + l16] = (bf16)(oacc[sub][nt][r] * inv);
                }
        }
    }
}

extern "C" void kernel_launch(void* const* d_in, const int* in_sizes, int n_in,
                              void* d_out, int out_size, void* d_ws, size_t ws_size,
                              hipStream_t stream) {
    const float* x      = (const float*)d_in[0];
    const float* w_qkv  = (const float*)d_in[1];
    const float* w_proj = (const float*)d_in[2];
    const float* b_proj = (const float*)d_in[3];
    float* out = (float*)d_out;
    char* ws = (char*)d_ws;

    bf16* xb  = (bf16*)(ws);                    // 8 MB
    bf16* wqb = (bf16*)(ws + ( 8u << 20));      // 6 MB
    bf16* wpb = (bf16*)(ws + (14u << 20));      // 2 MB
    bf16* Qb  = (bf16*)(ws + (16u << 20));      // 8 MB [bh][l][d]
    bf16* Kb  = (bf16*)(ws + (24u << 20));      // 8 MB [bh][l][d]
    bf16* VTb = (bf16*)(ws + (32u << 20));      // 8 MB [bh][d][l]
    bf16* AOb = (bf16*)(ws + (40u << 20));      // 8 MB [b*l][h*d]

    cvt_all<<<(C0 + C1 + C2) / 256, 256, 0, stream>>>(x, w_qkv, w_proj, xb, wqb, wpb);
    gemm_qkv<<<dim3(NQKV/128, BL/128), 256, 0, stream>>>(xb, wqb, Qb, Kb, VTb);
    attn<<<dim3(LL/256, BB*NH),        512, 0, stream>>>(Qb, Kb, VTb, AOb);
    gemm_proj<<<dim3(DIM/64, BL/128),  256, 0, stream>>>(AOb, wpb, b_proj, out);
}

// Round 5
// 164.061 us; speedup vs baseline: 1.4929x; 1.0161x over previous
//
#include <hip/hip_runtime.h>

#define DIM 1024
#define NH 16
#define HD 64
#define BB 2
#define LL 2048
#define BL (BB*LL)     // 4096
#define NQKV (3*DIM)   // 3072

typedef __bf16 bf16;
typedef __bf16 bf16x4 __attribute__((ext_vector_type(4)));
typedef __bf16 bf16x8 __attribute__((ext_vector_type(8)));
typedef float  f32x4  __attribute__((ext_vector_type(4)));

// 0.125 * log2(e): fold head-dim scale + base-2 conversion into Q
#define QSCALE 0.1803368801111204f

typedef __attribute__((address_space(3))) unsigned int lds_u32;
typedef __attribute__((address_space(1))) unsigned int glb_u32;

// async global->LDS, 16B per lane. LDS dest = wave-uniform base + lane*16.
__device__ __forceinline__ void gld_lds16(const bf16* g, bf16* l) {
    __builtin_amdgcn_global_load_lds((const glb_u32*)g, (lds_u32*)l, 16, 0, 0);
}

// One kernel for all three fp32->bf16 conversions.
#define C0 (BL*DIM/4)      // x     : 1048576 float4
#define C1 (NQKV*DIM/4)    // w_qkv :  786432
#define C2 (DIM*DIM/4)     // w_proj:  262144
__global__ __launch_bounds__(256) void cvt_all(const float* __restrict__ x,
        const float* __restrict__ wq, const float* __restrict__ wp,
        bf16* __restrict__ xb, bf16* __restrict__ wqb, bf16* __restrict__ wpb) {
    int i = blockIdx.x * 256 + threadIdx.x;
    const float* in; bf16* out; int j;
    if (i < C0)            { in = x;  out = xb;  j = i; }
    else if (i < C0 + C1)  { in = wq; out = wqb; j = i - C0; }
    else                   { in = wp; out = wpb; j = i - C0 - C1; }
    float4 f = ((const float4*)in)[j];
    bf16x4 o = { (bf16)f.x, (bf16)f.y, (bf16)f.z, (bf16)f.w };
    ((bf16x4*)out)[j] = o;
}

// QKV GEMM: 128x128 tile, BK=64, XOR-swizzled LDS, operand-swapped MFMA
// (A-op = W rows) -> vectorized Q/K stores, lane-contiguous V stores.
__global__ __launch_bounds__(256, 3) void gemm_qkv(
        const bf16* __restrict__ A, const bf16* __restrict__ W,
        bf16* __restrict__ Qb, bf16* __restrict__ Kb, bf16* __restrict__ VTb) {
    __shared__ bf16 As[128][64];   // x tile, swizzled: LDS[r][c] = glb[r][c^(r&7)]
    __shared__ bf16 Bs[128][64];   // W tile, swizzled
    const int tid = threadIdx.x;
    const int w = tid >> 6, lane = tid & 63, quad = lane >> 4, l16 = lane & 15;
    const int n0 = blockIdx.x * 128, m0 = blockIdx.y * 128;
    const int wm = (w & 1) * 64, wn = (w >> 1) * 64;
    f32x4 acc[4][4] = {};   // acc[tm(n)][tn(m)]
    for (int k0 = 0; k0 < DIM; k0 += 64) {
        #pragma unroll
        for (int i = 0; i < 4; ++i) {        // 1024 chunks per tensor, 4/thread
            int cb = w * 256 + i * 64;       // wave-uniform chunk base
            int gc = cb + lane;
            int r = gc >> 3;
            int cs = (gc & 7) ^ (r & 7);     // swizzled source chunk
            gld_lds16(A + (size_t)(m0 + r) * DIM + k0 + cs*8, &As[0][0] + cb * 8);
            gld_lds16(W + (size_t)(n0 + r) * DIM + k0 + cs*8, &Bs[0][0] + cb * 8);
        }
        __syncthreads();
        #pragma unroll
        for (int kc = 0; kc < 2; ++kc) {
            bf16x8 af[4], bfr[4];
            #pragma unroll
            for (int t = 0; t < 4; ++t) {
                int rw = wn + t*16 + l16;                 // W row (n)
                int cw = (kc*4 + quad) ^ (rw & 7);
                af[t] = *(const bf16x8*)(&Bs[0][0] + rw*64 + cw*8);
                int rx = wm + t*16 + l16;                 // x row (m)
                int cx = (kc*4 + quad) ^ (rx & 7);
                bfr[t] = *(const bf16x8*)(&As[0][0] + rx*64 + cx*8);
            }
            #pragma unroll
            for (int tm = 0; tm < 4; ++tm)
                #pragma unroll
                for (int tn = 0; tn < 4; ++tn)
                    acc[tm][tn] = __builtin_amdgcn_mfma_f32_16x16x32_bf16(
                                      af[tm], bfr[tn], acc[tm][tn], 0, 0, 0);
        }
        __syncthreads();
    }
    // D layout (swapped): row quad*4+r -> n, col l16 -> m
    const int which = n0 >> 10;   // uniform per block
    #pragma unroll
    for (int tm = 0; tm < 4; ++tm) {
        int nb = n0 + wn + tm*16 + quad*4;       // n base for this lane (r=0..3)
        int rem = nb & 1023, h = rem >> 6, db = rem & 63;
        #pragma unroll
        for (int tn = 0; tn < 4; ++tn) {
            int m = m0 + wm + tn*16 + l16;
            int b = m >> 11, l = m & 2047, bh = (b << 4) | h;
            if (which == 0) {
                bf16x4 q4 = { (bf16)(acc[tm][tn][0] * QSCALE),
                              (bf16)(acc[tm][tn][1] * QSCALE),
                              (bf16)(acc[tm][tn][2] * QSCALE),
                              (bf16)(acc[tm][tn][3] * QSCALE) };
                *(bf16x4*)(Qb + ((size_t)bh << 17) + ((size_t)l << 6) + db) = q4;
            } else if (which == 1) {
                bf16x4 k4 = { (bf16)acc[tm][tn][0], (bf16)acc[tm][tn][1],
                              (bf16)acc[tm][tn][2], (bf16)acc[tm][tn][3] };
                *(bf16x4*)(Kb + ((size_t)bh << 17) + ((size_t)l << 6) + db) = k4;
            } else {
                #pragma unroll
                for (int r = 0; r < 4; ++r)   // lanes contiguous in l: 32B chunks
                    VTb[((size_t)bh << 17) + ((size_t)(db + r) << 11) + l] =
                        (bf16)acc[tm][tn][r];
            }
        }
    }
}

// proj: 128(M)x64(N), BK=64, swizzled, operand-swapped, now DOUBLE-BUFFERED
// with 1-iter lookahead (attn-proven pattern): stage(t+1) issues right after
// the barrier, compute(t) runs from the other buffer, so the vmcnt drain at
// the top of t+1 waits on loads issued a full compute-phase earlier instead
// of just-issued ones. One barrier per K-step.
__global__ __launch_bounds__(256, 3) void gemm_proj(
        const bf16* __restrict__ A, const bf16* __restrict__ W,
        const float* __restrict__ bias, float* __restrict__ out) {
    __shared__ bf16 As[2][128][64];   // 32 KB
    __shared__ bf16 Bs[2][64][64];    // 16 KB
    const int tid = threadIdx.x;
    const int w = tid >> 6, lane = tid & 63, quad = lane >> 4, l16 = lane & 15;
    const int n0 = blockIdx.x * 64, m0 = blockIdx.y * 128;
    const int wm = (w & 1) * 64, wn = (w >> 1) * 32;
    f32x4 acc[2][4] = {};   // acc[tm(n)][tn(m)]

    auto stage = [&](int k0, int buf) {
        #pragma unroll
        for (int i = 0; i < 4; ++i) {        // A: 1024 chunks, 4/thread
            int cb = w * 256 + i * 64;
            int gc = cb + lane;
            int r = gc >> 3;
            int cs = (gc & 7) ^ (r & 7);
            gld_lds16(A + (size_t)(m0 + r) * DIM + k0 + cs*8,
                      &As[buf][0][0] + cb * 8);
        }
        #pragma unroll
        for (int i = 0; i < 2; ++i) {        // B: 512 chunks, 2/thread
            int cb = w * 128 + i * 64;
            int gc = cb + lane;
            int r = gc >> 3;
            int cs = (gc & 7) ^ (r & 7);
            gld_lds16(W + (size_t)(n0 + r) * DIM + k0 + cs*8,
                      &Bs[buf][0][0] + cb * 8);
        }
    };

    stage(0, 0);
    for (int ks = 0; ks < 16; ++ks) {
        const int cur = ks & 1;
        __syncthreads();                  // stage(ks) landed; buf^1 reads done
        if (ks < 15) stage((ks + 1) * 64, cur ^ 1);
        #pragma unroll
        for (int kc = 0; kc < 2; ++kc) {
            bf16x8 af[2], bfr[4];
            #pragma unroll
            for (int t = 0; t < 2; ++t) {
                int rw = wn + t*16 + l16;
                int cw = (kc*4 + quad) ^ (rw & 7);
                af[t] = *(const bf16x8*)(&Bs[cur][0][0] + rw*64 + cw*8);
            }
            #pragma unroll
            for (int t = 0; t < 4; ++t) {
                int rx = wm + t*16 + l16;
                int cx = (kc*4 + quad) ^ (rx & 7);
                bfr[t] = *(const bf16x8*)(&As[cur][0][0] + rx*64 + cx*8);
            }
            #pragma unroll
            for (int tm = 0; tm < 2; ++tm)
                #pragma unroll
                for (int tn = 0; tn < 4; ++tn)
                    acc[tm][tn] = __builtin_amdgcn_mfma_f32_16x16x32_bf16(
                                      af[tm], bfr[tn], acc[tm][tn], 0, 0, 0);
        }
    }
    #pragma unroll
    for (int tm = 0; tm < 2; ++tm) {
        int nb = n0 + wn + tm*16 + quad*4;
        float4 b4 = *(const float4*)&bias[nb];
        #pragma unroll
        for (int tn = 0; tn < 4; ++tn) {
            int m = m0 + wm + tn*16 + l16;
            float4 o4 = { acc[tm][tn][0] + b4.x, acc[tm][tn][1] + b4.y,
                          acc[tm][tn][2] + b4.z, acc[tm][tn][3] + b4.w };
            *(float4*)(out + (size_t)m * DIM + nb) = o4;
        }
    }
}

// Flash attention, QBLK=256 / 8 waves / kv-split, KVBLK=128: two 64-row
// kv-subtiles per barrier. Halves the barrier count (33->17) and doubles the
// MFMA run per phase, amortizing the per-iteration convoy+drain that the R4
// issue-count showed still costs ~2/3 of wall. Layouts: Ks/VTs become
// [buf][sub][64][64] -- each subtile keeps the R3-verified swizzles; a wave's
// kv-half (64 of 128) = subtile kvh, with the R1-verified kk in {0,1} loop
// selecting the 32-wide k-block inside it. All fragment maps unchanged.
__global__ __launch_bounds__(512, 2) void attn(
        const bf16* __restrict__ Qb, const bf16* __restrict__ Kb,
        const bf16* __restrict__ VTb, bf16* __restrict__ AO) {
    __shared__ __align__(16) char smem[66048];   // Ks 32KB | VTs 32KB | Lred
    bf16* KsP  = (bf16*)smem;                    // [buf][sub][64][64]
    bf16* VTsP = (bf16*)(smem + 32768);          // [buf][sub][64][64]
    const int tid = threadIdx.x;
    const int w = tid >> 6, lane = tid & 63, quad = lane >> 4, l16 = lane & 15;
    const int qw = w & 3, kvh = w >> 2;          // q-quarter, kv-half
    // Bijective XCD swizzle (nwg=256, 256%8==0): XCD x gets bh in [4x, 4x+3].
    const int linear = blockIdx.y * 8 + blockIdx.x;
    const int swz = (linear & 7) * 32 + (linear >> 3);
    const int qt = swz & 7, bh = swz >> 3;
    const bf16* Qg = Qb + ((size_t)bh << 17) + (size_t)(qt * 256) * 64;
    const bf16* Kg = Kb + ((size_t)bh << 17);
    const bf16* Vg = VTb + ((size_t)bh << 17);

    bf16x8 aq[4][2];   // aq[sub][kd]: Q[q=qw*64+sub*16+l16][d=kd*32+quad*8+..]
    #pragma unroll
    for (int sub = 0; sub < 4; ++sub)
        #pragma unroll
        for (int kd = 0; kd < 2; ++kd)
            aq[sub][kd] = *(const bf16x8*)(Qg + (size_t)(qw*64 + sub*16 + l16) * 64
                                           + kd*32 + quad*8);

    bf16x8 onesf = {};
    if (l16 == 0)
        #pragma unroll
        for (int j = 0; j < 8; ++j) onesf[j] = (bf16)1.0f;

    f32x4 oacc[4][4] = {};         // [sub][nt]: O[q=sub*16+quad*4+r][d=nt*16+l16]
    f32x4 lacc[4] = {};            // row-sums, valid at l16==0 lanes
    const f32x4 zero4 = {};
    bf16x8 ap[4][2];               // P regs: [sub][kk], packed kt, PV'd kt+1

    // 512 threads stage one 16B chunk per subtile (2 subtiles per tensor).
    auto stageK = [&](int kt, int buf) {
        #pragma unroll
        for (int sub = 0; sub < 2; ++sub) {
            int r = tid >> 3;
            int cs = (tid & 7) ^ (r & 7) ^ ((r >> 3) & 7) ^ ((r & 1) << 2); // fK
            gld_lds16(Kg + (size_t)(kt*128 + sub*64 + r) * 64 + cs*8,
                      KsP + (buf*2 + sub) * 4096 + tid*8);
        }
    };
    auto stageV = [&](int kt, int buf) {
        #pragma unroll
        for (int sub = 0; sub < 2; ++sub) {
            int r = tid >> 3;
            int cs = (tid & 7) ^ (r & 7) ^ ((r >> 3) & 7);                  // fV
            gld_lds16(Vg + (size_t)r * 2048 + kt*128 + sub*64 + cs*8,
                      VTsP + (buf*2 + sub) * 4096 + tid*8);
        }
    };
    // PV for register P-frags 'ap' (this wave's kv-half = subtile kvh)
    auto pv = [&](int pbuf) {
        __builtin_amdgcn_s_setprio(1);
        #pragma unroll
        for (int kk = 0; kk < 2; ++kk) {
            #pragma unroll
            for (int nt = 0; nt < 4; ++nt) {
                int row = nt*16 + l16;                      // d-dim row of VT
                int cp = (kk*4 + quad) ^ (row & 7) ^ ((row >> 3) & 7);
                bf16x8 bv = *(const bf16x8*)(VTsP + (pbuf*2 + kvh) * 4096
                                             + row*64 + cp*8);
                #pragma unroll
                for (int sub = 0; sub < 4; ++sub)
                    oacc[sub][nt] = __builtin_amdgcn_mfma_f32_16x16x32_bf16(
                                        ap[sub][kk], bv, oacc[sub][nt], 0, 0, 0);
            }
            #pragma unroll
            for (int sub = 0; sub < 4; ++sub)
                lacc[sub] = __builtin_amdgcn_mfma_f32_16x16x32_bf16(
                                ap[sub][kk], onesf, lacc[sub], 0, 0, 0);
        }
        __builtin_amdgcn_s_setprio(0);
    };

    // One pipeline step (128 kv). Barrier: K(kt)+V(kt-1) staging landed (loads
    // issued a full iteration ago); reads of buffers being overwritten done.
    auto body = [&](int kt, int cur) {
        __syncthreads();
        if (kt < 15) stageK(kt + 1, cur ^ 1);
        stageV(kt, cur);                      // read at iter kt+1 (or epilogue)

        // PV(kt-1): register P (old ap) + VTs[cur^1]
        if (kt > 0) pv(cur ^ 1);

        // S^T(kt) from Ks[cur][kvh]: A = K-frag (permuted rows), B = aq
        f32x4 s[4][2][2];   // [sub][kk][u]
        __builtin_amdgcn_s_setprio(1);
        #pragma unroll
        for (int kk = 0; kk < 2; ++kk)
            #pragma unroll
            for (int u = 0; u < 2; ++u) {
                int rk = kk*32 + ((l16 >> 2) << 3) + u*4 + (l16 & 3);
                int f = (rk & 7) ^ ((rk >> 3) & 7) ^ ((rk & 1) << 2);
                const bf16* kb = KsP + (cur*2 + kvh) * 4096 + rk*64;
                bf16x8 kf0 = *(const bf16x8*)(kb + ((0*4 + quad) ^ f)*8);
                bf16x8 kf1 = *(const bf16x8*)(kb + ((1*4 + quad) ^ f)*8);
                #pragma unroll
                for (int sub = 0; sub < 4; ++sub) {
                    s[sub][kk][u] = __builtin_amdgcn_mfma_f32_16x16x32_bf16(
                                        kf0, aq[sub][0], zero4, 0, 0, 0);
                    s[sub][kk][u] = __builtin_amdgcn_mfma_f32_16x16x32_bf16(
                                        kf1, aq[sub][1], s[sub][kk][u], 0, 0, 0);
                }
            }
        __builtin_amdgcn_s_setprio(0);

        // exp2 + pack P(kt); lane (quad,l16) holds
        // P[q=l16][kv = kvh*64 + kk*32 + quad*8 + u*4 + r].
        #pragma unroll
        for (int sub = 0; sub < 4; ++sub)
            #pragma unroll
            for (int kk = 0; kk < 2; ++kk) {
                bf16x8 p;
                #pragma unroll
                for (int u = 0; u < 2; ++u)
                    #pragma unroll
                    for (int r = 0; r < 4; ++r)
                        p[u*4 + r] = (bf16)__builtin_amdgcn_exp2f(s[sub][kk][u][r]);
                ap[sub][kk] = p;
            }
    };

    stageK(0, 0);
    for (int kt2 = 0; kt2 < 16; kt2 += 2) {
        body(kt2,     0);
        body(kt2 + 1, 1);
    }
    __syncthreads();   // V(15) staging landed for all waves
    pv(1);             // final PV(15)

    // Combine kv-halves: wave w+4 adds into wave w via LDS (staging reuse).
    // Two rounds of 2 writer-waves (2 x 16KB = 32KB fits the K region).
    float* OredF = (float*)smem;            // [slot2][sub4][row16][d64]
    float* LredF = (float*)(smem + 32768);  // [slot2][sub4][row16]
    const int b = bh >> 4, h = bh & 15;
    #pragma unroll
    for (int t = 0; t < 2; ++t) {
        __syncthreads();
        if (kvh == 1 && (qw >> 1) == t) {
            int slot = qw & 1;
            #pragma unroll
            for (int sub = 0; sub < 4; ++sub)
                #pragma unroll
                for (int nt = 0; nt < 4; ++nt)
                    #pragma unroll
                    for (int r = 0; r < 4; ++r)
                        OredF[((slot*4 + sub)*16 + quad*4 + r)*64 + nt*16 + l16]
                            = oacc[sub][nt][r];
            if (l16 == 0)
                #pragma unroll
                for (int sub = 0; sub < 4; ++sub)
                    #pragma unroll
                    for (int r = 0; r < 4; ++r)
                        LredF[(slot*4 + sub)*16 + quad*4 + r] = lacc[sub][r];
        }
        __syncthreads();
        if (kvh == 0 && (qw >> 1) == t) {
            int slot = qw & 1;
            #pragma unroll
            for (int sub = 0; sub < 4; ++sub)
                #pragma unroll
                for (int nt = 0; nt < 4; ++nt)
                    #pragma unroll
                    for (int r = 0; r < 4; ++r)
                        oacc[sub][nt][r] +=
                            OredF[((slot*4 + sub)*16 + quad*4 + r)*64 + nt*16 + l16];
            if (l16 == 0)
                #pragma unroll
                for (int sub = 0; sub < 4; ++sub)
                    #pragma unroll
                    for (int r = 0; r < 4; ++r)
                        lacc[sub][r] += LredF[(slot*4 + sub)*16 + quad*4 + r];
            #pragma unroll
            for (int sub = 0; sub < 4; ++sub)
                #pragma unroll
                for (int r = 0; r < 4; ++r) {
                    float l = __shfl(lacc[sub][r], quad * 16, 64);
                    float inv = 1.0f / l;
                    int lq = qt*256 + qw*64 + sub*16 + quad*4 + r;
                    size_t rowbase = ((size_t)(b * 2048 + lq)) * DIM + h * 64;
                    #pragma unroll
                    for (int nt = 0; nt < 4; ++nt)
                        AO[rowbase + nt*16 + l16] = (bf16)(oacc[sub][nt][r] * inv);
                }
        }
    }
}

extern "C" void kernel_launch(void* const* d_in, const int* in_sizes, int n_in,
                              void* d_out, int out_size, void* d_ws, size_t ws_size,
                              hipStream_t stream) {
    const float* x      = (const float*)d_in[0];
    const float* w_qkv  = (const float*)d_in[1];
    const float* w_proj = (const float*)d_in[2];
    const float* b_proj = (const float*)d_in[3];
    float* out = (float*)d_out;
    char* ws = (char*)d_ws;

    bf16* xb  = (bf16*)(ws);                    // 8 MB
    bf16* wqb = (bf16*)(ws + ( 8u << 20));      // 6 MB
    bf16* wpb = (bf16*)(ws + (14u << 20));      // 2 MB
    bf16* Qb  = (bf16*)(ws + (16u << 20));      // 8 MB [bh][l][d]
    bf16* Kb  = (bf16*)(ws + (24u << 20));      // 8 MB [bh][l][d]
    bf16* VTb = (bf16*)(ws + (32u << 20));      // 8 MB [bh][d][l]
    bf16* AOb = (bf16*)(ws + (40u << 20));      // 8 MB [b*l][h*d]

    cvt_all<<<(C0 + C1 + C2) / 256, 256, 0, stream>>>(x, w_qkv, w_proj, xb, wqb, wpb);
    gemm_qkv<<<dim3(NQKV/128, BL/128), 256, 0, stream>>>(xb, wqb, Qb, Kb, VTb);
    attn<<<dim3(LL/256, BB*NH),        512, 0, stream>>>(Qb, Kb, VTb, AOb);
    gemm_proj<<<dim3(DIM/64, BL/128),  256, 0, stream>>>(AOb, wpb, b_proj, out);
}